// Round 1
// baseline (79.914 us; speedup 1.0000x reference)
//
#include <hip/hip_runtime.h>

#define G 64
#define K 4            // anchors per thread
#define POS_THR 0.5f
#define NEG_THR 0.4f
#define WB_STRIDE 512  // floats per batch row in staging buffer (2 KB)

// Staging buffer written by compact_kernel, read by ssd_target_kernel.
// Per b: [float4 box x64 | float2 (area, cls) x64 | int nv]
// Static __device__ memory: independent of d_ws (which the harness poisons),
// fully rewritten (all slots < nv, plus slot 0 when nv==0) every replay.
__device__ float g_ws[32 * WB_STRIDE];

__global__ __launch_bounds__(64) void compact_kernel(
    const float* __restrict__ gt_boxes,   // (B, G, 5)
    const int*   __restrict__ gt_class)   // (B, G, 2)
{
    const int b = blockIdx.x;
    const int g = threadIdx.x;            // 64 threads == one wave, all lanes active
    const float* p = gt_boxes + ((size_t)b * G + g) * 5;
    const float y1 = p[0], x1 = p[1], y2 = p[2], x2 = p[3], tagv = p[4];
    const bool valid = (tagv != 0.0f);
    const unsigned long long m = __ballot(valid);
    const int pos = __popcll(m & ((1ull << g) - 1ull));   // order-preserving compaction
    const float cls = (float)gt_class[((size_t)b * G + g) * 2 + 0];
    float* wb = g_ws + (size_t)b * WB_STRIDE;
    if (valid) {
        reinterpret_cast<float4*>(wb)[pos] = make_float4(y1, x1, y2, x2);
        // ref order: (gx2-gx1)*(gy2-gy1)
        reinterpret_cast<float2*>(wb + 256)[pos] = make_float2((x2 - x1) * (y2 - y1), cls);
    }
    if (g == 0) {
        reinterpret_cast<int*>(wb + 384)[0] = __popcll(m);
        if (m == 0ull) {  // all invalid: ref matches gt[0] (argmax of all -1 == 0)
            reinterpret_cast<float4*>(wb)[0] = make_float4(y1, x1, y2, x2);
            reinterpret_cast<float2*>(wb + 256)[0] = make_float2(0.0f, cls);
        }
    }
}

__global__ __launch_bounds__(256) void ssd_target_kernel(
    const float* __restrict__ anchors,    // (A, 4)
    float* __restrict__ out,              // [deltas B*A*4 | class B*A | tag B*A]
    int A, int B)
{
    // LDS mirror only for the divergent [win] lookups in the epilogue and the
    // rare exact-fallback loop; the hot loop reads g_ws with wave-uniform
    // addresses (SMEM / constant-cache path, LDS pipe stays free).
    __shared__ float s_ws[G * 6];         // 384 floats

    const int b = blockIdx.y;
    const float* __restrict__ wb = g_ws + (size_t)b * WB_STRIDE;

    const int t = threadIdx.x;
    for (int j = t; j < 384; j += 256) s_ws[j] = wb[j];

    const int a0 = blockIdx.x * (256 * K) + t;     // stride-256 anchors => coalesced

    float4 an[K];
    float  area_an[K];
    #pragma unroll
    for (int k = 0; k < K; ++k) {
        an[k] = reinterpret_cast<const float4*>(anchors)[a0 + k * 256];
        area_an[k] = (an[k].w - an[k].y) * (an[k].z - an[k].x);
    }

    const int nv = reinterpret_cast<const int*>(wb + 384)[0];   // uniform scalar load

    float best[K], second[K];
    int   bg[K];
    #pragma unroll
    for (int k = 0; k < K; ++k) { best[k] = -1.0f; second[k] = -1.0f; bg[k] = 0; }

    // ---- Pass 1: approx IoU via v_rcp; one uniform (SGPR) gt load feeds K anchors.
    // Top-2 + first-occurrence argmax; top-2 relative gap > 1e-5 (40x the
    // ~2^-22 rcp error bound) proves approx argmax == exact-rounded argmax.
    #pragma unroll 4
    for (int i = 0; i < nv; ++i) {
        const float4 gb = reinterpret_cast<const float4*>(wb)[i];
        const float  ga = reinterpret_cast<const float2*>(wb + 256)[i].x;
        #pragma unroll
        for (int k = 0; k < K; ++k) {
            float iw = fmaxf(0.0f, fminf(gb.w, an[k].w) - fmaxf(gb.y, an[k].y));
            float ih = fmaxf(0.0f, fminf(gb.z, an[k].z) - fmaxf(gb.x, an[k].x));
            float inter = iw * ih;
            float denom = ga + area_an[k] - inter;
            float apx = inter * __builtin_amdgcn_rcpf(denom);
            bg[k]     = (apx > best[k]) ? i : bg[k];         // strict > : first occurrence
            // runner-up update: median(second, apx, best) == max(second, min(apx, best))
            second[k] = __builtin_amdgcn_fmed3f(second[k], apx, best[k]);
            best[k]   = fmaxf(best[k], apx);
        }
    }

    __syncthreads();   // s_ws mirror ready (uniform control flow up to here)

    const float4* s_box = reinterpret_cast<const float4*>(s_ws);
    const float2* s_ac  = reinterpret_cast<const float2*>(s_ws + 256);

    #pragma unroll
    for (int k = 0; k < K; ++k) {
        const float ay1 = an[k].x, ax1 = an[k].y, ay2 = an[k].z, ax2 = an[k].w;
        int   win = bg[k];
        float q;                    // exact-rounded iou_max (reference parity)
        if (nv == 0) {
            q = -1.0f; win = 0;     // ref: all ious -1, argmax = 0
        } else {
            // best==0 => every inter==0 exactly in both approx and exact;
            // winner = first valid box, no fallback needed.
            const bool need_exact =
                (best[k] > 0.0f) && (second[k] >= best[k] * (1.0f - 1e-5f));
            if (need_exact) {
                // Rare near-tie: replicate reference bit-for-bit (IEEE div).
                float be = -1.0f; int bi = 0;
                for (int i = 0; i < nv; ++i) {
                    const float4 gb = s_box[i];
                    float iw = fmaxf(0.0f, fminf(gb.w, ax2) - fmaxf(gb.y, ax1));
                    float ih = fmaxf(0.0f, fminf(gb.z, ay2) - fmaxf(gb.x, ay1));
                    float inter = iw * ih;
                    float denom = s_ac[i].x + area_an[k] - inter;
                    float iou = inter / denom;               // IEEE div
                    if (iou > be) { be = iou; bi = i; }
                }
                q = be; win = bi;
            } else {
                // Unique winner: one exact IEEE div for the tag thresholds.
                const float4 gb = s_box[win];
                float iw = fmaxf(0.0f, fminf(gb.w, ax2) - fmaxf(gb.y, ax1));
                float ih = fmaxf(0.0f, fminf(gb.z, ay2) - fmaxf(gb.x, ay1));
                float inter = iw * ih;
                float denom = s_ac[win].x + area_an[k] - inter;
                q = inter / denom;                           // IEEE div
            }
        }

        const float4 gb = s_box[win];                        // divergent lookup -> LDS
        const float h  = ay2 - ay1;
        const float w  = ax2 - ax1;
        const float rh = __builtin_amdgcn_rcpf(h);
        const float rw = __builtin_amdgcn_rcpf(w);
        const float cy = (ay2 + ay1) * 0.5f;
        const float cx = (ax2 + ax1) * 0.5f;
        const float gh  = gb.z - gb.x;
        const float gw  = gb.w - gb.y;
        const float gcy = (gb.z + gb.x) * 0.5f;
        const float gcx = (gb.w + gb.y) * 0.5f;

        // deltas have ~5.28 absmax slack: rcp/log2 approx (err ~1e-6) is safe.
        const float dy = (gcy - cy) * rh * 10.0f;
        const float dx = (gcx - cx) * rw * 10.0f;
        const float dh = __log2f(gh * rh) * 3.4657359028f;   // ln(x)*5
        const float dw = __log2f(gw * rw) * 3.4657359028f;

        const float tag = (q >= POS_THR) ? 1.0f : ((q < NEG_THR) ? -1.0f : 0.0f);

        const size_t idx = (size_t)b * A + (size_t)(a0 + k * 256);
        float4 d; d.x = dy; d.y = dx; d.z = dh; d.w = dw;
        reinterpret_cast<float4*>(out)[idx] = d;             // deltas
        out[(size_t)B * A * 4 + idx] = s_ac[win].y;          // class_ids (as float)
        out[(size_t)B * A * 5 + idx] = tag;                  // anchors_tag
    }
}

extern "C" void kernel_launch(void* const* d_in, const int* in_sizes, int n_in,
                              void* d_out, int out_size, void* d_ws, size_t ws_size,
                              hipStream_t stream) {
    const float* gt_boxes = (const float*)d_in[0];  // (B, G, 5) fp32
    const int*   gt_class = (const int*)d_in[1];    // (B, G, 2) int32
    const float* anchors  = (const float*)d_in[2];  // (A, 4)   fp32
    float* out = (float*)d_out;

    const int B = in_sizes[0] / (G * 5);            // 16
    const int A = in_sizes[2] / 4;                  // 65536

    compact_kernel<<<dim3(B), dim3(64), 0, stream>>>(gt_boxes, gt_class);

    dim3 grid(A / (256 * K), B);
    dim3 block(256);
    ssd_target_kernel<<<grid, block, 0, stream>>>(anchors, out, A, B);
}

// Round 2
// 77.300 us; speedup vs baseline: 1.0338x; 1.0338x over previous
//
#include <hip/hip_runtime.h>

#define G 64
#define K 4            // anchors per thread
#define POS_THR 0.5f
#define NEG_THR 0.4f

__global__ __launch_bounds__(256) void ssd_target_kernel(
    const float* __restrict__ gt_boxes,   // (B, G, 5)
    const int*   __restrict__ gt_class,   // (B, G, 2)
    const float* __restrict__ anchors,    // (A, 4)
    float* __restrict__ out,              // [deltas B*A*4 | class B*A | tag B*A]
    int A, int B)
{
    // Compacted valid-gt arrays (order-preserving => argmax tie-break identical).
    // Single kernel: no cross-kernel L2 coherence boundary, one graph node.
    __shared__ float4 s_box[G];            // (y1, x1, y2, x2)
    __shared__ float2 s_ac[G];             // (area, cls)
    __shared__ int    s_nv;

    const int b = blockIdx.y;
    const int t = threadIdx.x;
    const int a0 = blockIdx.x * (256 * K) + t;     // stride-256 anchors => coalesced

    // Issue anchor loads FIRST: vmcnt overlaps the wave-0 compaction + barrier.
    float4 an[K];
    #pragma unroll
    for (int k = 0; k < K; ++k)
        an[k] = reinterpret_cast<const float4*>(anchors)[a0 + k * 256];

    if (t < G) {   // threads 0..63 == wave 0, all lanes active
        const int g = t;
        const float* p = gt_boxes + ((size_t)b * G + g) * 5;
        const float y1 = p[0], x1 = p[1], y2 = p[2], x2 = p[3], tagv = p[4];
        const bool valid = (tagv != 0.0f);
        const unsigned long long m = __ballot(valid);
        const int pos = __popcll(m & ((1ull << g) - 1ull));  // order-preserving
        const float cls = (float)gt_class[((size_t)b * G + g) * 2 + 0];
        if (valid) {
            s_box[pos] = make_float4(y1, x1, y2, x2);
            // ref order: (gx2-gx1)*(gy2-gy1)
            s_ac[pos]  = make_float2((x2 - x1) * (y2 - y1), cls);
        }
        if (g == 0) {
            s_nv = __popcll(m);
            if (m == 0ull) {  // all invalid: ref matches gt[0] (argmax of all -1 == 0)
                s_box[0] = make_float4(y1, x1, y2, x2);
                s_ac[0]  = make_float2(0.0f, cls);
            }
        }
    }
    __syncthreads();

    float area_an[K];
    #pragma unroll
    for (int k = 0; k < K; ++k)
        area_an[k] = (an[k].w - an[k].y) * (an[k].z - an[k].x);

    const int nv = s_nv;
    float best[K], second[K];
    int   bg[K];
    #pragma unroll
    for (int k = 0; k < K; ++k) { best[k] = -1.0f; second[k] = -1.0f; bg[k] = 0; }

    // ---- Pass 1: approx IoU via v_rcp; one LDS b128+b32 (broadcast, conflict-free)
    // feeds K=4 anchors. Top-2 + first-occurrence argmax; top-2 relative gap
    // > 1e-5 (40x the ~2^-22 rcp error bound) proves approx argmax == exact argmax.
    #pragma unroll 4
    for (int i = 0; i < nv; ++i) {
        const float4 gb = s_box[i];
        const float  ga = s_ac[i].x;
        #pragma unroll
        for (int k = 0; k < K; ++k) {
            float iw = fmaxf(0.0f, fminf(gb.w, an[k].w) - fmaxf(gb.y, an[k].y));
            float ih = fmaxf(0.0f, fminf(gb.z, an[k].z) - fmaxf(gb.x, an[k].x));
            float inter = iw * ih;
            float denom = ga + area_an[k] - inter;
            float apx = inter * __builtin_amdgcn_rcpf(denom);
            bg[k]     = (apx > best[k]) ? i : bg[k];         // strict > : first occurrence
            // runner-up update: median(second, apx, best) == max(second, min(apx, best))
            second[k] = __builtin_amdgcn_fmed3f(second[k], apx, best[k]);
            best[k]   = fmaxf(best[k], apx);
        }
    }

    #pragma unroll
    for (int k = 0; k < K; ++k) {
        const float ay1 = an[k].x, ax1 = an[k].y, ay2 = an[k].z, ax2 = an[k].w;
        int   win = bg[k];
        float q;                    // exact-rounded iou_max (reference parity)
        if (nv == 0) {
            q = -1.0f; win = 0;     // ref: all ious -1, argmax = 0
        } else {
            // best==0 => every inter==0 exactly in both approx and exact;
            // winner = first valid box, no fallback needed.
            const bool need_exact =
                (best[k] > 0.0f) && (second[k] >= best[k] * (1.0f - 1e-5f));
            if (need_exact) {
                // Rare near-tie: replicate reference bit-for-bit (IEEE div).
                float be = -1.0f; int bi = 0;
                for (int i = 0; i < nv; ++i) {
                    const float4 gb = s_box[i];
                    float iw = fmaxf(0.0f, fminf(gb.w, ax2) - fmaxf(gb.y, ax1));
                    float ih = fmaxf(0.0f, fminf(gb.z, ay2) - fmaxf(gb.x, ay1));
                    float inter = iw * ih;
                    float denom = s_ac[i].x + area_an[k] - inter;
                    float iou = inter / denom;               // IEEE div
                    if (iou > be) { be = iou; bi = i; }
                }
                q = be; win = bi;
            } else {
                // Unique winner: one exact IEEE div for the tag thresholds.
                const float4 gb = s_box[win];
                float iw = fmaxf(0.0f, fminf(gb.w, ax2) - fmaxf(gb.y, ax1));
                float ih = fmaxf(0.0f, fminf(gb.z, ay2) - fmaxf(gb.x, ay1));
                float inter = iw * ih;
                float denom = s_ac[win].x + area_an[k] - inter;
                q = inter / denom;                           // IEEE div
            }
        }

        const float4 gb = s_box[win];                        // divergent lookup -> LDS
        const float h  = ay2 - ay1;
        const float w  = ax2 - ax1;
        const float rh = __builtin_amdgcn_rcpf(h);
        const float rw = __builtin_amdgcn_rcpf(w);
        const float cy = (ay2 + ay1) * 0.5f;
        const float cx = (ax2 + ax1) * 0.5f;
        const float gh  = gb.z - gb.x;
        const float gw  = gb.w - gb.y;
        const float gcy = (gb.z + gb.x) * 0.5f;
        const float gcx = (gb.w + gb.y) * 0.5f;

        // deltas have ~5.28 absmax slack: rcp/log2 approx (err ~1e-6) is safe.
        const float dy = (gcy - cy) * rh * 10.0f;
        const float dx = (gcx - cx) * rw * 10.0f;
        const float dh = __log2f(gh * rh) * 3.4657359028f;   // ln(x)*5
        const float dw = __log2f(gw * rw) * 3.4657359028f;

        const float tag = (q >= POS_THR) ? 1.0f : ((q < NEG_THR) ? -1.0f : 0.0f);

        const size_t idx = (size_t)b * A + (size_t)(a0 + k * 256);
        float4 d; d.x = dy; d.y = dx; d.z = dh; d.w = dw;
        reinterpret_cast<float4*>(out)[idx] = d;             // deltas
        out[(size_t)B * A * 4 + idx] = s_ac[win].y;          // class_ids (as float)
        out[(size_t)B * A * 5 + idx] = tag;                  // anchors_tag
    }
}

extern "C" void kernel_launch(void* const* d_in, const int* in_sizes, int n_in,
                              void* d_out, int out_size, void* d_ws, size_t ws_size,
                              hipStream_t stream) {
    const float* gt_boxes = (const float*)d_in[0];  // (B, G, 5) fp32
    const int*   gt_class = (const int*)d_in[1];    // (B, G, 2) int32
    const float* anchors  = (const float*)d_in[2];  // (A, 4)   fp32
    float* out = (float*)d_out;

    const int B = in_sizes[0] / (G * 5);            // 16
    const int A = in_sizes[2] / 4;                  // 65536

    dim3 grid(A / (256 * K), B);
    dim3 block(256);
    ssd_target_kernel<<<grid, block, 0, stream>>>(gt_boxes, gt_class, anchors, out, A, B);
}